// Round 19
// baseline (127.062 us; speedup 1.0000x reference)
//
#include <hip/hip_runtime.h>
#include <hip/hip_bf16.h>

// SparseLinear forward: R17/18 panel-skip GEMM + GLOBALLY BALANCED frag deal.
// One global compaction order (nonzero rows -> slots 0..Mc-1, zeros after);
// 16-row fragment chunks are dealt round-robin to panels: panel bm's local
// frag j holds global slots ((j*16+bm)*16 + 0..15). Every panel then has
// mfp = ceil((F-bm)/16) in {8,9} (F = ceil(Mc/16)) -> total active frags
// drops ~135 -> F~128.5 and the makespan block drops from mfp 9-10 to 8-9.
// Only build_map + index transforms change vs R18; staging coalescing
// (4 threads per 64B row-chunk), lean-sync counted-vmcnt ledger, A 2-deep +
// B 3-deep rings (160 KiB), zero-conflict granule-XOR swizzle, register-held
// B, setprio, SLOT guards, rowmap-scatter fused-bias epilogue all unchanged.
// Output is bitwise-deterministic under atomic slot-assignment order (each
// row's K-accumulation order is slot-invariant; zero rows get exact bias).

typedef __bf16 bf16x8 __attribute__((ext_vector_type(8)));
typedef float f32x4 __attribute__((ext_vector_type(4)));

constexpr int M = 4096;   // T*B
constexpr int N = 4096;   // C_OUT
constexpr int K = 4096;   // C_IN
constexpr int BM = 256, BN = 256, BK = 64;
constexpr int NT = K / BK;          // 64 K-tiles
constexpr int A_BUF = 16384;        // elems per A buffer (2 units: k0,k1)
constexpr int B_BASE = 32768;       // elem offset of B region
constexpr int B_SLOT = 16384;       // elems per B slot (2 units: k0,k1)

__device__ int g_nzflag[M];         // per-row nonzero flag
__device__ int g_cnt;               // global nonzero count (Mc)
__device__ int g_zcnt;              // global zero count
__device__ int g_rowmap[M];         // global slot -> original row

__device__ __forceinline__ unsigned short f2bf_rne(float f) {
    unsigned int u = __float_as_uint(f);
    u += 0x7fffu + ((u >> 16) & 1u);   // round-to-nearest-even
    return (unsigned short)(u >> 16);
}

__global__ __launch_bounds__(256) void reset_flags() {
    const int i = blockIdx.x * 256 + threadIdx.x;
    if (i < M) g_nzflag[i] = 0;
    if (i == 0) { g_cnt = 0; g_zcnt = 0; }
}

// Pure streaming convert (x->Abf, w->Bbf) + fused zero-row detection.
__global__ __launch_bounds__(256) void prep_cvt(
    const float* __restrict__ x, const float* __restrict__ w,
    unsigned short* __restrict__ Abf, unsigned short* __restrict__ Bbf)
{
    const int n8 = (M * K) / 8;
    int idx = blockIdx.x * blockDim.x + threadIdx.x;
    int stride = gridDim.x * blockDim.x;
    for (int i = idx; i < 2 * n8; i += stride) {
        const float* src;
        unsigned short* dst;
        bool isx;
        long b;
        if (i < n8) { b = (long)i * 8;        src = x + b; dst = Abf + b; isx = true; }
        else        { b = (long)(i - n8) * 8; src = w + b; dst = Bbf + b; isx = false; }
        float4 v0 = *(const float4*)(src);
        float4 v1 = *(const float4*)(src + 4);
        ushort4 r0, r1;
        r0.x = f2bf_rne(v0.x); r0.y = f2bf_rne(v0.y);
        r0.z = f2bf_rne(v0.z); r0.w = f2bf_rne(v0.w);
        r1.x = f2bf_rne(v1.x); r1.y = f2bf_rne(v1.y);
        r1.z = f2bf_rne(v1.z); r1.w = f2bf_rne(v1.w);
        *(ushort4*)(dst) = r0;
        *(ushort4*)(dst + 4) = r1;
        if (isx) {
            const bool nz8 = (v0.x != 0.f) | (v0.y != 0.f) | (v0.z != 0.f) |
                             (v0.w != 0.f) | (v1.x != 0.f) | (v1.y != 0.f) |
                             (v1.z != 0.f) | (v1.w != 0.f);
            if (__any(nz8) && (threadIdx.x & 63) == 0) {
                atomicOr(&g_nzflag[i >> 9], 1);   // row = i*8/4096
            }
        }
    }
}

// Global compaction: nonzero rows -> front slots, zero rows -> back slots.
__global__ __launch_bounds__(256) void build_map() {
    const int r = blockIdx.x * 256 + threadIdx.x;
    const int flag = g_nzflag[r];
    const int pos = flag ? atomicAdd(&g_cnt, 1) : (M - 1) - atomicAdd(&g_zcnt, 1);
    g_rowmap[pos] = r;
}

// Stage one B k-half unit ([256 rows][32 k], 2 global_load_lds / thread).
__device__ __forceinline__ void stage_unit(const unsigned short* __restrict__ g,
                                           size_t grow0, int kcol0,
                                           unsigned short* unitbase,
                                           int tid, int wave) {
#pragma unroll
    for (int i = 0; i < 2; ++i) {
        const int row = i * 128 + (tid >> 2);
        const int cg  = (tid & 3) ^ ((row >> 1) & 3);
        const unsigned short* src = g + (grow0 + (size_t)row) * (size_t)K
                                      + (size_t)(kcol0 + cg * 8);
        unsigned short* dst = unitbase + i * 4096 + wave * 512;
        __builtin_amdgcn_global_load_lds(
            (const __attribute__((address_space(1))) void*)src,
            (__attribute__((address_space(3))) void*)dst, 16, 0, 0);
    }
}

// Stage one A k-half unit through the dealt row permutation. hi==false skips
// the 128..255 slab (never read when mfp <= 8); block-uniform counts.
__device__ __forceinline__ void stageA_ind(const unsigned short* __restrict__ g,
                                           int rowA0, int rowA1, int kcol0,
                                           unsigned short* unitbase,
                                           int tid, int wave, bool hi) {
    {
        const int slotrow = tid >> 2;
        const int cg  = (tid & 3) ^ ((slotrow >> 1) & 3);
        const unsigned short* src = g + (size_t)rowA0 * (size_t)K
                                      + (size_t)(kcol0 + cg * 8);
        unsigned short* dst = unitbase + wave * 512;
        __builtin_amdgcn_global_load_lds(
            (const __attribute__((address_space(1))) void*)src,
            (__attribute__((address_space(3))) void*)dst, 16, 0, 0);
    }
    if (hi) {
        const int slotrow = 128 + (tid >> 2);
        const int cg  = (tid & 3) ^ ((slotrow >> 1) & 3);
        const unsigned short* src = g + (size_t)rowA1 * (size_t)K
                                      + (size_t)(kcol0 + cg * 8);
        unsigned short* dst = unitbase + 4096 + wave * 512;
        __builtin_amdgcn_global_load_lds(
            (const __attribute__((address_space(1))) void*)src,
            (__attribute__((address_space(3))) void*)dst, 16, 0, 0);
    }
}

// One fragment slot S (frag = wr + 2*S): 2 A-reads (k0,k1) x held b[4][2],
// 8 MFMA. Guard is wave-uniform; skipped slots keep acc=0.
#define SLOT(S)                                                                \
    if (wr + 2 * (S) < mfp) {                                                  \
        bf16x8 ak0 = *(const bf16x8*)(pA0 + (S) * 1024);                       \
        bf16x8 ak1 = *(const bf16x8*)(pA1 + (S) * 1024);                       \
        __builtin_amdgcn_s_setprio(1);                                         \
        _Pragma("unroll")                                                      \
        for (int n = 0; n < 4; ++n)                                            \
            acc[S][n] = __builtin_amdgcn_mfma_f32_16x16x32_bf16(               \
                ak0, b[n][0], acc[S][n], 0, 0, 0);                             \
        _Pragma("unroll")                                                      \
        for (int n = 0; n < 4; ++n)                                            \
            acc[S][n] = __builtin_amdgcn_mfma_f32_16x16x32_bf16(               \
                ak1, b[n][1], acc[S][n], 0, 0, 0);                             \
        __builtin_amdgcn_s_setprio(0);                                         \
    }

__global__ __launch_bounds__(512, 2) void gemm_bal(
    const unsigned short* __restrict__ A,   // [M][K] bf16 (original order)
    const unsigned short* __restrict__ B,   // [N][K] bf16
    const float* __restrict__ bias,         // [N]
    float* __restrict__ C)                  // [M][N] fp32 (rowmap scatter)
{
    __shared__ unsigned short lds[81920];   // 160 KiB: A 2-deep + B 3-deep

    // XCD-aware bijective swizzle: 256 wgs, 256 % 8 == 0
    const int wg = blockIdx.x;
    const int s  = ((wg & 7) << 5) | (wg >> 3);
    const int bm = s >> 4, bn = s & 15;
    const size_t bcol = (size_t)bn * BN;

    // Balanced deal: panel bm's local frag j = global frag j*16+bm.
    const int Mc = *(volatile int*)&g_cnt;
    const int F  = (Mc + 15) >> 4;                 // global active frags
    const int df = F - bm;
    const int mfp = (df > 0) ? ((df + 15) >> 4 < 16 ? (df + 15) >> 4 : 16) : 0;
    const bool hi = (mfp > 8);

    const int tid  = threadIdx.x;
    const int wave = tid >> 6;
    const int lane = tid & 63;
    const int wr = wave >> 2;       // 0..1 : owns frags wr+2m (interleaved)
    const int wc = wave & 3;        // 0..3  (4 N-waves, 64 cols each)
    const int lr = lane & 15;       // fragment row-in-16
    const int kg = lane >> 4;       // k-group 0..3

    const int a_row0 = wr * 16 + lr;          // frag wr base rows (slot space)
    const int b_row0 = wc * 64 + lr;
    const int aoff = a_row0 * 32 + ((kg ^ ((a_row0 >> 1) & 3)) << 3);
    const int boff = b_row0 * 32 + ((kg ^ ((b_row0 >> 1) & 3)) << 3);

    // Per-thread A staging source rows via the deal transform:
    // slot row sr -> global slot (sr>>4)*256 + bm*16 + (sr&15).
    const int srl = tid >> 2;
    const int gsl = ((srl >> 4) << 8) + (bm << 4) + (srl & 15);
    const int rowA0 = g_rowmap[gsl];
    const int rowA1 = g_rowmap[gsl + 2048];    // sr+128 -> +8*256

    f32x4 acc[8][4];
#pragma unroll
    for (int m = 0; m < 8; ++m)
#pragma unroll
        for (int n = 0; n < 4; ++n)
            acc[m][n] = (f32x4){0.f, 0.f, 0.f, 0.f};

    // ---- prologue: B(0), A(0), B(1) (B(1) newest) ----
    stage_unit(B, bcol, 0,       lds + B_BASE, tid, wave);
    stage_unit(B, bcol, 32,      lds + B_BASE + 8192, tid, wave);
    stageA_ind(A, rowA0, rowA1, 0,  lds, tid, wave, hi);
    stageA_ind(A, rowA0, rowA1, 32, lds + 8192, tid, wave, hi);
    stage_unit(B, bcol, BK,      lds + B_BASE + B_SLOT, tid, wave);
    stage_unit(B, bcol, BK + 32, lds + B_BASE + B_SLOT + 8192, tid, wave);

    int bs = 0;   // B ring slot of tile t
    for (int t = 0; t < NT; ++t) {
        const bool pf1 = (t + 1) < NT;
        const bool pf2 = (t + 2) < NT;

        // Entry wait: retains the 4 newest loads = B of the next tile
        // (count-robust to A issuing 2 or 4 loads).
        if (pf1) { asm volatile("s_waitcnt vmcnt(4)" ::: "memory"); }
        else     { asm volatile("s_waitcnt vmcnt(0)" ::: "memory"); }
        __builtin_amdgcn_s_barrier();

        unsigned short* aB = lds + (t & 1) * A_BUF;
        unsigned short* ao = lds + ((t & 1) ^ 1) * A_BUF;    // A stage target
        unsigned short* bb = lds + B_BASE + bs * B_SLOT;
        const int bs2 = (bs + 2 >= 3) ? bs - 1 : bs + 2;     // (t+2)%3
        unsigned short* b2 = lds + B_BASE + bs2 * B_SLOT;    // B stage target

        const unsigned short* pA0 = aB + aoff;
        const unsigned short* pA1 = aB + 8192 + aoff;

        // ===== B-frags for whole tile (register-held) =====
        bf16x8 b[4][2];
#pragma unroll
        for (int n = 0; n < 4; ++n) {
            b[n][0] = *(const bf16x8*)(bb + boff + n * 512);
            b[n][1] = *(const bf16x8*)(bb + 8192 + boff + n * 512);
        }

        if (pf1) stageA_ind(A, rowA0, rowA1, (t + 1) * BK, ao, tid, wave, hi);
        SLOT(0) SLOT(1)
        if (pf1) stageA_ind(A, rowA0, rowA1, (t + 1) * BK + 32, ao + 8192, tid, wave, hi);
        SLOT(2) SLOT(3)
        if (pf2) stage_unit(B, bcol, (t + 2) * BK, b2, tid, wave);
        SLOT(4) SLOT(5)
        if (pf2) stage_unit(B, bcol, (t + 2) * BK + 32, b2 + 8192, tid, wave);
        SLOT(6) SLOT(7)

        bs = (bs + 1 >= 3) ? 0 : bs + 1;
    }

    // ---- epilogue: scatter via dealt rowmap; skipped slots store bias ----
#pragma unroll
    for (int n = 0; n < 4; ++n) {
        const size_t col = bcol + wc * 64 + n * 16 + lr;
        const float bs_ = bias[col];
#pragma unroll
        for (int m = 0; m < 8; ++m) {
            const int fj = wr + 2 * m;                        // local frag
#pragma unroll
            for (int j = 0; j < 4; ++j) {
                const size_t orow =
                    (size_t)g_rowmap[(fj << 8) + (bm << 4) + kg * 4 + j];
                C[orow * N + col] = acc[m][n][j] + bs_;
            }
        }
    }
}

extern "C" void kernel_launch(void* const* d_in, const int* in_sizes, int n_in,
                              void* d_out, int out_size, void* d_ws, size_t ws_size,
                              hipStream_t stream) {
    const float* x    = (const float*)d_in[0];   // [T,B,C_IN] = [M,K]
    const float* w    = (const float*)d_in[1];   // [C_OUT,C_IN] = [N,K]
    const float* bias = (const float*)d_in[2];   // [N]
    float* out = (float*)d_out;                  // [M,N]

    unsigned short* Abf = (unsigned short*)d_ws;           // 32 MiB
    unsigned short* Bbf = Abf + (size_t)M * K;             // 32 MiB

    reset_flags<<<16, 256, 0, stream>>>();
    prep_cvt<<<4096, 256, 0, stream>>>(x, w, Abf, Bbf);
    build_map<<<16, 256, 0, stream>>>();
    gemm_bal<<<dim3((M / BM) * (N / BN)), 512, 0, stream>>>(Abf, Bbf, bias, out);
}

// Round 20
// 122.728 us; speedup vs baseline: 1.0353x; 1.0353x over previous
//
#include <hip/hip_runtime.h>
#include <hip/hip_bf16.h>

// SparseLinear forward — FINAL consolidation (R20).
// GEMM = R19's gemm_bal (90.9us): lean-sync 256x256 bf16 MFMA GEMM with
// globally-balanced fragment deal over compacted nonzero rows (~50% zero-row
// skip), ONE counted vmcnt + ONE barrier per K-tile, A 2-deep + B 3-deep LDS
// rings (160 KiB), zero-conflict granule-XOR swizzle, register-held B,
// slot-skip guards, rowmap-scatter fused-bias epilogue.
// R20 trims fixed overhead: reset_flags launch eliminated (prep writes
// per-row-part verdicts via plain stores — every slot rewritten every call),
// build_map collapsed to a single block (shared-atomic compaction, no global
// counters needing reset). 3 launches total.

typedef __bf16 bf16x8 __attribute__((ext_vector_type(8)));
typedef float f32x4 __attribute__((ext_vector_type(4)));

constexpr int M = 4096;   // T*B
constexpr int N = 4096;   // C_OUT
constexpr int K = 4096;   // C_IN
constexpr int BM = 256, BN = 256, BK = 64;
constexpr int NT = K / BK;          // 64 K-tiles
constexpr int A_BUF = 16384;        // elems per A buffer (2 units: k0,k1)
constexpr int B_BASE = 32768;       // elem offset of B region
constexpr int B_SLOT = 16384;       // elems per B slot (2 units: k0,k1)

__device__ int g_nzpart[M * 8];     // per-(row,eighth) nonzero verdict
__device__ int g_cnt;               // global nonzero count (Mc)
__device__ int g_rowmap[M];         // global slot -> original row

__device__ __forceinline__ unsigned short f2bf_rne(float f) {
    unsigned int u = __float_as_uint(f);
    u += 0x7fffu + ((u >> 16) & 1u);   // round-to-nearest-even
    return (unsigned short)(u >> 16);
}

// Pure streaming convert (x->Abf, w->Bbf). Each wave's 64 lanes cover 512
// contiguous elems = one (row, eighth) of x; lane 0 stores the wave verdict
// (plain store, slot rewritten every call -> no reset kernel needed).
__global__ __launch_bounds__(256) void prep_cvt(
    const float* __restrict__ x, const float* __restrict__ w,
    unsigned short* __restrict__ Abf, unsigned short* __restrict__ Bbf)
{
    const int n8 = (M * K) / 8;
    int idx = blockIdx.x * blockDim.x + threadIdx.x;
    int stride = gridDim.x * blockDim.x;
    for (int i = idx; i < 2 * n8; i += stride) {
        const float* src;
        unsigned short* dst;
        bool isx;
        long b;
        if (i < n8) { b = (long)i * 8;        src = x + b; dst = Abf + b; isx = true; }
        else        { b = (long)(i - n8) * 8; src = w + b; dst = Bbf + b; isx = false; }
        float4 v0 = *(const float4*)(src);
        float4 v1 = *(const float4*)(src + 4);
        ushort4 r0, r1;
        r0.x = f2bf_rne(v0.x); r0.y = f2bf_rne(v0.y);
        r0.z = f2bf_rne(v0.z); r0.w = f2bf_rne(v0.w);
        r1.x = f2bf_rne(v1.x); r1.y = f2bf_rne(v1.y);
        r1.z = f2bf_rne(v1.z); r1.w = f2bf_rne(v1.w);
        *(ushort4*)(dst) = r0;
        *(ushort4*)(dst + 4) = r1;
        if (isx) {
            const bool nz8 = (v0.x != 0.f) | (v0.y != 0.f) | (v0.z != 0.f) |
                             (v0.w != 0.f) | (v1.x != 0.f) | (v1.y != 0.f) |
                             (v1.z != 0.f) | (v1.w != 0.f);
            const unsigned long long m = __ballot(nz8);
            if ((threadIdx.x & 63) == 0) {
                g_nzpart[i >> 6] = (m != 0ull);   // (row, eighth) index
            }
        }
    }
}

// Single-block global compaction: nonzero rows -> slots 0..Mc-1, zeros after.
// Shared-atomic counters (no global state to reset). Slot order within the
// nonzero/zero groups is nondeterministic but the OUTPUT is bitwise-
// deterministic: each row's K-accumulation order is slot-invariant and zero
// rows produce exact bias.
__global__ __launch_bounds__(1024) void build_map1() {
    __shared__ int s_cnz, s_cz;
    if (threadIdx.x == 0) { s_cnz = 0; s_cz = 0; }
    __syncthreads();
    for (int r = threadIdx.x; r < M; r += 1024) {
        int f = 0;
#pragma unroll
        for (int p = 0; p < 8; ++p) f |= g_nzpart[r * 8 + p];
        const int pos = f ? atomicAdd(&s_cnz, 1) : (M - 1) - atomicAdd(&s_cz, 1);
        g_rowmap[pos] = r;
    }
    __syncthreads();
    if (threadIdx.x == 0) g_cnt = s_cnz;
}

// Stage one B k-half unit ([256 rows][32 k], 2 global_load_lds / thread).
__device__ __forceinline__ void stage_unit(const unsigned short* __restrict__ g,
                                           size_t grow0, int kcol0,
                                           unsigned short* unitbase,
                                           int tid, int wave) {
#pragma unroll
    for (int i = 0; i < 2; ++i) {
        const int row = i * 128 + (tid >> 2);
        const int cg  = (tid & 3) ^ ((row >> 1) & 3);
        const unsigned short* src = g + (grow0 + (size_t)row) * (size_t)K
                                      + (size_t)(kcol0 + cg * 8);
        unsigned short* dst = unitbase + i * 4096 + wave * 512;
        __builtin_amdgcn_global_load_lds(
            (const __attribute__((address_space(1))) void*)src,
            (__attribute__((address_space(3))) void*)dst, 16, 0, 0);
    }
}

// Stage one A k-half unit through the dealt row permutation. hi==false skips
// the 128..255 slab (never read when mfp <= 8); block-uniform counts.
__device__ __forceinline__ void stageA_ind(const unsigned short* __restrict__ g,
                                           int rowA0, int rowA1, int kcol0,
                                           unsigned short* unitbase,
                                           int tid, int wave, bool hi) {
    {
        const int slotrow = tid >> 2;
        const int cg  = (tid & 3) ^ ((slotrow >> 1) & 3);
        const unsigned short* src = g + (size_t)rowA0 * (size_t)K
                                      + (size_t)(kcol0 + cg * 8);
        unsigned short* dst = unitbase + wave * 512;
        __builtin_amdgcn_global_load_lds(
            (const __attribute__((address_space(1))) void*)src,
            (__attribute__((address_space(3))) void*)dst, 16, 0, 0);
    }
    if (hi) {
        const int slotrow = 128 + (tid >> 2);
        const int cg  = (tid & 3) ^ ((slotrow >> 1) & 3);
        const unsigned short* src = g + (size_t)rowA1 * (size_t)K
                                      + (size_t)(kcol0 + cg * 8);
        unsigned short* dst = unitbase + 4096 + wave * 512;
        __builtin_amdgcn_global_load_lds(
            (const __attribute__((address_space(1))) void*)src,
            (__attribute__((address_space(3))) void*)dst, 16, 0, 0);
    }
}

// One fragment slot S (frag = wr + 2*S): 2 A-reads (k0,k1) x held b[4][2],
// 8 MFMA. Guard is wave-uniform; skipped slots keep acc=0.
#define SLOT(S)                                                                \
    if (wr + 2 * (S) < mfp) {                                                  \
        bf16x8 ak0 = *(const bf16x8*)(pA0 + (S) * 1024);                       \
        bf16x8 ak1 = *(const bf16x8*)(pA1 + (S) * 1024);                       \
        __builtin_amdgcn_s_setprio(1);                                         \
        _Pragma("unroll")                                                      \
        for (int n = 0; n < 4; ++n)                                            \
            acc[S][n] = __builtin_amdgcn_mfma_f32_16x16x32_bf16(               \
                ak0, b[n][0], acc[S][n], 0, 0, 0);                             \
        _Pragma("unroll")                                                      \
        for (int n = 0; n < 4; ++n)                                            \
            acc[S][n] = __builtin_amdgcn_mfma_f32_16x16x32_bf16(               \
                ak1, b[n][1], acc[S][n], 0, 0, 0);                             \
        __builtin_amdgcn_s_setprio(0);                                         \
    }

__global__ __launch_bounds__(512, 2) void gemm_bal(
    const unsigned short* __restrict__ A,   // [M][K] bf16 (original order)
    const unsigned short* __restrict__ B,   // [N][K] bf16
    const float* __restrict__ bias,         // [N]
    float* __restrict__ C)                  // [M][N] fp32 (rowmap scatter)
{
    __shared__ unsigned short lds[81920];   // 160 KiB: A 2-deep + B 3-deep

    // XCD-aware bijective swizzle: 256 wgs, 256 % 8 == 0
    const int wg = blockIdx.x;
    const int s  = ((wg & 7) << 5) | (wg >> 3);
    const int bm = s >> 4, bn = s & 15;
    const size_t bcol = (size_t)bn * BN;

    // Balanced deal: panel bm's local frag j = global frag j*16+bm.
    const int Mc = *(volatile int*)&g_cnt;
    const int F  = (Mc + 15) >> 4;                 // global active frags
    const int df = F - bm;
    const int mfp = (df > 0) ? ((df + 15) >> 4 < 16 ? (df + 15) >> 4 : 16) : 0;
    const bool hi = (mfp > 8);

    const int tid  = threadIdx.x;
    const int wave = tid >> 6;
    const int lane = tid & 63;
    const int wr = wave >> 2;       // 0..1 : owns frags wr+2m (interleaved)
    const int wc = wave & 3;        // 0..3  (4 N-waves, 64 cols each)
    const int lr = lane & 15;       // fragment row-in-16
    const int kg = lane >> 4;       // k-group 0..3

    const int a_row0 = wr * 16 + lr;          // frag wr base rows (slot space)
    const int b_row0 = wc * 64 + lr;
    const int aoff = a_row0 * 32 + ((kg ^ ((a_row0 >> 1) & 3)) << 3);
    const int boff = b_row0 * 32 + ((kg ^ ((b_row0 >> 1) & 3)) << 3);

    // Per-thread A staging source rows via the deal transform:
    // slot row sr -> global slot (sr>>4)*256 + bm*16 + (sr&15).
    const int srl = tid >> 2;
    const int gsl = ((srl >> 4) << 8) + (bm << 4) + (srl & 15);
    const int rowA0 = g_rowmap[gsl];
    const int rowA1 = g_rowmap[gsl + 2048];    // sr+128 -> +8*256

    f32x4 acc[8][4];
#pragma unroll
    for (int m = 0; m < 8; ++m)
#pragma unroll
        for (int n = 0; n < 4; ++n)
            acc[m][n] = (f32x4){0.f, 0.f, 0.f, 0.f};

    // ---- prologue: B(0), A(0), B(1) (B(1) newest) ----
    stage_unit(B, bcol, 0,       lds + B_BASE, tid, wave);
    stage_unit(B, bcol, 32,      lds + B_BASE + 8192, tid, wave);
    stageA_ind(A, rowA0, rowA1, 0,  lds, tid, wave, hi);
    stageA_ind(A, rowA0, rowA1, 32, lds + 8192, tid, wave, hi);
    stage_unit(B, bcol, BK,      lds + B_BASE + B_SLOT, tid, wave);
    stage_unit(B, bcol, BK + 32, lds + B_BASE + B_SLOT + 8192, tid, wave);

    int bs = 0;   // B ring slot of tile t
    for (int t = 0; t < NT; ++t) {
        const bool pf1 = (t + 1) < NT;
        const bool pf2 = (t + 2) < NT;

        // Entry wait: retains the 4 newest loads = B of the next tile
        // (count-robust to A issuing 2 or 4 loads).
        if (pf1) { asm volatile("s_waitcnt vmcnt(4)" ::: "memory"); }
        else     { asm volatile("s_waitcnt vmcnt(0)" ::: "memory"); }
        __builtin_amdgcn_s_barrier();

        unsigned short* aB = lds + (t & 1) * A_BUF;
        unsigned short* ao = lds + ((t & 1) ^ 1) * A_BUF;    // A stage target
        unsigned short* bb = lds + B_BASE + bs * B_SLOT;
        const int bs2 = (bs + 2 >= 3) ? bs - 1 : bs + 2;     // (t+2)%3
        unsigned short* b2 = lds + B_BASE + bs2 * B_SLOT;    // B stage target

        const unsigned short* pA0 = aB + aoff;
        const unsigned short* pA1 = aB + 8192 + aoff;

        // ===== B-frags for whole tile (register-held) =====
        bf16x8 b[4][2];
#pragma unroll
        for (int n = 0; n < 4; ++n) {
            b[n][0] = *(const bf16x8*)(bb + boff + n * 512);
            b[n][1] = *(const bf16x8*)(bb + 8192 + boff + n * 512);
        }

        if (pf1) stageA_ind(A, rowA0, rowA1, (t + 1) * BK, ao, tid, wave, hi);
        SLOT(0) SLOT(1)
        if (pf1) stageA_ind(A, rowA0, rowA1, (t + 1) * BK + 32, ao + 8192, tid, wave, hi);
        SLOT(2) SLOT(3)
        if (pf2) stage_unit(B, bcol, (t + 2) * BK, b2, tid, wave);
        SLOT(4) SLOT(5)
        if (pf2) stage_unit(B, bcol, (t + 2) * BK + 32, b2 + 8192, tid, wave);
        SLOT(6) SLOT(7)

        bs = (bs + 1 >= 3) ? 0 : bs + 1;
    }

    // ---- epilogue: scatter via dealt rowmap; skipped slots store bias ----
#pragma unroll
    for (int n = 0; n < 4; ++n) {
        const size_t col = bcol + wc * 64 + n * 16 + lr;
        const float bs_ = bias[col];
#pragma unroll
        for (int m = 0; m < 8; ++m) {
            const int fj = wr + 2 * m;                        // local frag
#pragma unroll
            for (int j = 0; j < 4; ++j) {
                const size_t orow =
                    (size_t)g_rowmap[(fj << 8) + (bm << 4) + kg * 4 + j];
                C[orow * N + col] = acc[m][n][j] + bs_;
            }
        }
    }
}

extern "C" void kernel_launch(void* const* d_in, const int* in_sizes, int n_in,
                              void* d_out, int out_size, void* d_ws, size_t ws_size,
                              hipStream_t stream) {
    const float* x    = (const float*)d_in[0];   // [T,B,C_IN] = [M,K]
    const float* w    = (const float*)d_in[1];   // [C_OUT,C_IN] = [N,K]
    const float* bias = (const float*)d_in[2];   // [N]
    float* out = (float*)d_out;                  // [M,N]

    unsigned short* Abf = (unsigned short*)d_ws;           // 32 MiB
    unsigned short* Bbf = Abf + (size_t)M * K;             // 32 MiB

    prep_cvt<<<4096, 256, 0, stream>>>(x, w, Abf, Bbf);
    build_map1<<<1, 1024, 0, stream>>>();
    gemm_bal<<<dim3((M / BM) * (N / BN)), 512, 0, stream>>>(Abf, Bbf, bias, out);
}